// Round 6
// baseline (326.089 us; speedup 1.0000x reference)
//
#include <hip/hip_runtime.h>
#include <cstddef>

#define EPS_ 1e-6f

typedef unsigned short u16;
typedef __attribute__((ext_vector_type(8))) short short8;      // bf16x8 MFMA frag
typedef __attribute__((ext_vector_type(8))) unsigned short us8;
typedef __attribute__((ext_vector_type(4))) unsigned short us4;
typedef __attribute__((ext_vector_type(4))) float f32x4;

__device__ __forceinline__ float sigmoidf_(float x){ return 1.0f/(1.0f+__expf(-x)); }
__device__ __forceinline__ float sigmoidf_fast(float x){
  return __builtin_amdgcn_rcpf(1.0f+__expf(-x));
}
__device__ __forceinline__ u16 f2bf(float x){
  union { __bf16 b; u16 u; } c; c.b = (__bf16)x; return c.u;
}
__device__ __forceinline__ float bf2f(u16 u){
  union { unsigned i; float f; } c; c.i = ((unsigned)u) << 16; return c.f;
}
// two float4 (8 consecutive k-floats) -> bf16x8 MFMA A-fragment
__device__ __forceinline__ short8 cvt8(float4 a, float4 b){
  short8 r;
  r[0]=(short)f2bf(a.x); r[1]=(short)f2bf(a.y); r[2]=(short)f2bf(a.z); r[3]=(short)f2bf(a.w);
  r[4]=(short)f2bf(b.x); r[5]=(short)f2bf(b.y); r[6]=(short)f2bf(b.z); r[7]=(short)f2bf(b.w);
  return r;
}

// ---------------------------------------------------------------------------
// prep_w: emit W in MFMA B-FRAGMENT order (1KB contiguous wave loads).
// WTf[((eb*8+it)*64 + lane)*8 + j] = bf16(W[d][e]),
//   e = eb*16 + (lane&15), d = it*32 + (lane>>4)*8 + j.
// ---------------------------------------------------------------------------
__global__ __launch_bounds__(256) void prep_w(const float* __restrict__ Wq,
                                              const float* __restrict__ Wk,
                                              u16* __restrict__ WqT,
                                              u16* __restrict__ WkT){
  const int m  = blockIdx.x >> 4;
  const int eb = blockIdx.x & 15;
  const float* W = m ? Wk : Wq;
  u16* WTf = m ? WkT : WqT;
  const int t = threadIdx.x;
  #pragma unroll
  for (int rep = 0; rep < 2; rep++) {
    const int lin  = rep*256 + t;
    const int it   = lin >> 6;
    const int lane = lin & 63;
    const int q    = lane >> 4;
    const int i16  = lane & 15;
    us8 o;
    #pragma unroll
    for (int j = 0; j < 8; j++)
      o[j] = f2bf(W[(it*32 + q*8 + j)*256 + eb*16 + i16]);
    *(us8*)&WTf[(size_t)((eb*8 + it)*512 + lane*8)] = o;
  }
}

// ---------------------------------------------------------------------------
// phi_k v5: NO A-LDS staging. Each lane streams its own MFMA A-fragment
// floats directly from K in fragment order (3-slot, distance-2 rotation),
// converting f32->bf16 at consume time. GEMM1 is one continuous load+MFMA
// stream -> no staging burst, no staging barrier, HBM demand spread evenly.
// Per load instr: 16 rows x 32B; h=0/1 pair completes a 128B-aligned span
// per row -> all 64B lines fully consumed (no over-fetch).
// Epilogue (T2 transpose + colsum) = round-4 verbatim.
// ---------------------------------------------------------------------------
__global__ __launch_bounds__(256, 2) void phi_k(
    const float* __restrict__ K, const u16* __restrict__ WkT,
    const float* __restrict__ bk,
    u16* __restrict__ phi_kT, float* __restrict__ colsum)
{
  __shared__ u16 T2[128][136];     // 34816 B transpose epilogue

  const int t = threadIdx.x;
  const int l = t & 63;
  const int wf = t >> 6;
  const int i16 = l & 15, q = l >> 4;
  const int row0 = blockIdx.x * 64;

  const float* abase = K + (size_t)(row0 + i16)*256 + q*8;
  const u16* wbf = WkT + (size_t)wf*16384 + (size_t)l*8;

  // ---- prologue: A-stream slots 0,1 ; W-stream slots 0,1 ----
  float4 av[3][4][2];
  #pragma unroll
  for (int pit = 0; pit < 2; pit++)
    #pragma unroll
    for (int mi=0;mi<4;mi++)
      #pragma unroll
      for (int h=0;h<2;h++)
        av[pit][mi][h] = *(const float4*)(abase + (size_t)mi*4096 + pit*32 + h*4);

  short8 Bfr[3][4];
  #pragma unroll
  for (int fi=0;fi<4;fi++) Bfr[0][fi] = *(const short8*)&wbf[fi*4096];
  #pragma unroll
  for (int fi=0;fi<4;fi++) Bfr[1][fi] = *(const short8*)&wbf[fi*4096 + 512];

  f32x4 acc[4][4];
  #pragma unroll
  for (int i=0;i<4;i++)
    #pragma unroll
    for (int j=0;j<4;j++) acc[i][j] = (f32x4){0.f,0.f,0.f,0.f};

  #pragma unroll
  for (int it = 0; it < 8; it++) {
    short8 af[4];
    #pragma unroll
    for (int mi=0;mi<4;mi++)
      af[mi] = cvt8(av[it%3][mi][0], av[it%3][mi][1]);
    if (it < 6) {
      #pragma unroll
      for (int mi=0;mi<4;mi++)
        #pragma unroll
        for (int h=0;h<2;h++)
          av[(it+2)%3][mi][h] = *(const float4*)(abase + (size_t)mi*4096 + (it+2)*32 + h*4);
      #pragma unroll
      for (int fi=0;fi<4;fi++)
        Bfr[(it+2)%3][fi] = *(const short8*)&wbf[fi*4096 + (it+2)*512];
    }
    #pragma unroll
    for (int mi=0;mi<4;mi++)
      #pragma unroll
      for (int fi=0;fi<4;fi++)
        acc[mi][fi] = __builtin_amdgcn_mfma_f32_16x16x32_bf16(af[mi], Bfr[it%3][fi], acc[mi][fi], 0,0,0);
  }

  float bv[4];
  #pragma unroll
  for (int fi=0;fi<4;fi++) bv[fi] = bk[wf*64 + fi*16 + i16];

  // ---- transpose epilogue (round-4 structure) ----
  const int b      = row0 >> 12;
  const int nchunk = (row0 & 4095) >> 6;
  #pragma unroll
  for (int h = 0; h < 2; h++) {
    if ((wf >> 1) == h) {
      #pragma unroll
      for (int fi=0;fi<4;fi++) {
        float cp = 0.f;
        #pragma unroll
        for (int mi=0;mi<4;mi++) {
          #pragma unroll
          for (int r=0;r<4;r++) {
            float ph = sigmoidf_fast(acc[mi][fi][r] + bv[fi]);
            cp += ph;
            T2[(wf*64 + fi*16 + i16) & 127][mi*16 + q*4 + r] = f2bf(ph);
          }
        }
        cp += __shfl_xor(cp,16); cp += __shfl_xor(cp,32);
        if (l < 16) atomicAdd(&colsum[b*256 + wf*64 + fi*16 + l], cp);
      }
    }
    __syncthreads();
    {
      const size_t gb = ((size_t)(b*64 + nchunk)*256 + h*128) * 64;
      #pragma unroll
      for (int j=0;j<4;j++) {
        const int g = (j*256 + t) * 8;
        *(us8*)&phi_kT[gb + g] = *(const us8*)&T2[g >> 6][g & 63];
      }
    }
    if (h == 0) __syncthreads();
  }
}

// ---------------------------------------------------------------------------
// KV partials (round-5 structure, nc=8): phi_kT tiled reads, E=exp(...),
// fragment-flat partsT stores (contiguous 512B), denom f32 atomics.
// ---------------------------------------------------------------------------
__global__ __launch_bounds__(256) void kv_kernel(const u16* __restrict__ phi_kT,
    const float* __restrict__ V, const float* __restrict__ colsum,
    u16* __restrict__ partsT, float* __restrict__ denom)
{
  __shared__ u16 phiT_lds[256][72];   // [d][n 64]
  __shared__ u16 E_lds[64][72];       // [e][n 64]

  const int t = threadIdx.x;
  const int l = t & 63;
  const int w = t >> 6;
  const int e0 = blockIdx.x * 64;
  const int nc = blockIdx.y;          // 0..7
  const int b  = blockIdx.z;
  const int i16 = l & 15, q = l >> 4;

  const int sd = t >> 3;
  const int sn = (t & 7) * 8;

  const size_t cbase = (size_t)(b*64 + nc*8) * 16384;

  us8  rA[8];
  float rV[16];
  #pragma unroll
  for (int p=0;p<8;p++)
    rA[p] = *(const us8*)&phi_kT[cbase + (size_t)(sd + 32*p)*64 + sn];
  #pragma unroll
  for (int j=0;j<16;j++)
    rV[j] = V[(size_t)(b*4096 + nc*512 + w*16 + j)*256 + e0 + l];

  const float inv_cs = 1.0f / (colsum[b*256 + e0 + l] + EPS_);
  float dsum = 0.f;

  f32x4 acc[4][4];
  #pragma unroll
  for (int i=0;i<4;i++)
    #pragma unroll
    for (int j=0;j<4;j++) acc[i][j] = (f32x4){0.f,0.f,0.f,0.f};

  for (int c = 0; c < 8; c++) {
    #pragma unroll
    for (int p=0;p<8;p++) *(us8*)&phiT_lds[sd + 32*p][sn] = rA[p];
    __syncthreads();
    if (c < 7) {
      const size_t nb = cbase + (size_t)(c+1)*16384;
      #pragma unroll
      for (int p=0;p<8;p++)
        rA[p] = *(const us8*)&phi_kT[nb + (size_t)(sd + 32*p)*64 + sn];
    }
    us8 pv0 = *(const us8*)&phiT_lds[e0 + l][w*16];
    us8 pv1 = *(const us8*)&phiT_lds[e0 + l][w*16 + 8];
    us8 ev0, ev1;
    #pragma unroll
    for (int j=0;j<8;j++) {
      float ef = __expf(bf2f(pv0[j]) * inv_cs * rV[j]);
      dsum += ef; ev0[j] = f2bf(ef);
    }
    #pragma unroll
    for (int j=0;j<8;j++) {
      float ef = __expf(bf2f(pv1[j]) * inv_cs * rV[8+j]);
      dsum += ef; ev1[j] = f2bf(ef);
    }
    *(us8*)&E_lds[l][w*16]     = ev0;
    *(us8*)&E_lds[l][w*16 + 8] = ev1;
    if (c < 7) {
      #pragma unroll
      for (int j=0;j<16;j++)
        rV[j] = V[(size_t)(b*4096 + nc*512 + (c+1)*64 + w*16 + j)*256 + e0 + l];
    }
    __syncthreads();
    #pragma unroll
    for (int kk=0;kk<2;kk++){
      const int ko = kk*32 + q*8;
      short8 af[4], bfr[4];
      #pragma unroll
      for (int mi=0;mi<4;mi++) af[mi]  = *(const short8*)&phiT_lds[w*64 + mi*16 + i16][ko];
      #pragma unroll
      for (int ei=0;ei<4;ei++) bfr[ei] = *(const short8*)&E_lds[ei*16 + i16][ko];
      #pragma unroll
      for (int mi=0;mi<4;mi++)
        #pragma unroll
        for (int ei=0;ei<4;ei++)
          acc[mi][ei] = __builtin_amdgcn_mfma_f32_16x16x32_bf16(af[mi], bfr[ei], acc[mi][ei],0,0,0);
    }
    __syncthreads();
  }

  atomicAdd(&denom[b*256 + e0 + l], dsum);

  u16* slice = partsT + (size_t)(nc*16 + b) * 65536 + (size_t)blockIdx.x * 16384;
  #pragma unroll
  for (int mi=0;mi<4;mi++)
    #pragma unroll
    for (int ei=0;ei<4;ei++) {
      us4 o;
      #pragma unroll
      for (int r=0;r<4;r++) o[r] = f2bf(acc[mi][ei][r]);
      *(us4*)&slice[(size_t)(((w*16 + mi*4 + ei)*64 + l)*4)] = o;
    }
}

// ---------------------------------------------------------------------------
// kv_norm: reduce fragment-flat partsT over 8 nc slices, divide by denom,
// emit KV_n in MFMA B-FRAGMENT order.
// ---------------------------------------------------------------------------
__global__ __launch_bounds__(256) void kv_norm(const u16* __restrict__ partsT,
    const float* __restrict__ denom, u16* __restrict__ KV_nT)
{
  const int t = threadIdx.x;
  const int b = blockIdx.y;
  const int s4 = blockIdx.x*256 + t;
  const int e0b = s4 >> 12;
  const int rem = s4 & 4095;
  const int comb = rem >> 6;
  const int l = rem & 63;
  const int w  = comb >> 4;
  const int mi = (comb >> 2) & 3;
  const int ei = comb & 3;
  const int e  = e0b*64 + ei*16 + (l & 15);
  const int d0 = w*64 + mi*16 + (l >> 4)*4;

  const float dn = denom[b*256 + e];
  float s0=0.f,s1=0.f,s2=0.f,s3=0.f;
  #pragma unroll 4
  for (int nc=0;nc<8;nc++){
    us4 v = *(const us4*)&partsT[(size_t)(nc*16 + b)*65536 + (size_t)s4*4];
    s0+=bf2f(v[0]); s1+=bf2f(v[1]); s2+=bf2f(v[2]); s3+=bf2f(v[3]);
  }
  us4 o; o[0]=f2bf(s0/dn); o[1]=f2bf(s1/dn); o[2]=f2bf(s2/dn); o[3]=f2bf(s3/dn);

  const int eb  = e >> 4;
  const int i16 = e & 15;
  const int it  = d0 >> 5;
  const int qo  = (d0 >> 3) & 3;
  const int j0  = d0 & 4;
  *(us4*)&KV_nT[(size_t)b*65536 + (size_t)((eb*8 + it)*512 + (qo*16 + i16)*8 + j0)] = o;
}

// ---------------------------------------------------------------------------
// out_fused v3: GEMM1's A (Q tile) streamed per-lane from global in fragment
// order (no A-LDS, no staging burst). Epilogue1 (sigmoid + block-local
// rowsum -> S in LDS) and GEMM2 (fragment-order KV stream) = round-4
// verbatim. 2 barriers total.
// ---------------------------------------------------------------------------
__global__ __launch_bounds__(256, 2) void out_fused(
    const float* __restrict__ Q, const u16* __restrict__ WqT,
    const float* __restrict__ bq, const u16* __restrict__ KV_nT,
    float* __restrict__ outp)
{
  __shared__ u16 S[64][264];
  __shared__ float rs_sh[64];

  const int t = threadIdx.x;
  const int l = t & 63;
  const int wf = t >> 6;
  const int i16 = l & 15, q = l >> 4;
  const int n0 = blockIdx.x * 64;
  const int b  = blockIdx.y;

  if (t < 64) rs_sh[t] = 0.f;
  __syncthreads();   // rs zero visible before any wave's epilogue atomics

  const float* abase = Q + (size_t)(b*4096 + n0 + i16)*256 + q*8;
  const u16* wbf = WqT + (size_t)wf*16384 + (size_t)l*8;
  const u16* kbf = KV_nT + (size_t)b*65536 + (size_t)wf*16384 + (size_t)l*8;

  // ---- GEMM1: phi = Q_tile @ Wq, A streamed from global ----
  float4 av[3][4][2];
  #pragma unroll
  for (int pit = 0; pit < 2; pit++)
    #pragma unroll
    for (int mi=0;mi<4;mi++)
      #pragma unroll
      for (int h=0;h<2;h++)
        av[pit][mi][h] = *(const float4*)(abase + (size_t)mi*4096 + pit*32 + h*4);

  short8 Bfr[3][4];
  #pragma unroll
  for (int fi=0;fi<4;fi++) Bfr[0][fi] = *(const short8*)&wbf[fi*4096];
  #pragma unroll
  for (int fi=0;fi<4;fi++) Bfr[1][fi] = *(const short8*)&wbf[fi*4096 + 512];

  f32x4 acc[4][4];
  #pragma unroll
  for (int i=0;i<4;i++)
    #pragma unroll
    for (int j=0;j<4;j++) acc[i][j] = (f32x4){0.f,0.f,0.f,0.f};

  #pragma unroll
  for (int it = 0; it < 8; it++) {
    short8 af[4];
    #pragma unroll
    for (int mi=0;mi<4;mi++)
      af[mi] = cvt8(av[it%3][mi][0], av[it%3][mi][1]);
    if (it < 6) {
      #pragma unroll
      for (int mi=0;mi<4;mi++)
        #pragma unroll
        for (int h=0;h<2;h++)
          av[(it+2)%3][mi][h] = *(const float4*)(abase + (size_t)mi*4096 + (it+2)*32 + h*4);
      #pragma unroll
      for (int fi=0;fi<4;fi++)
        Bfr[(it+2)%3][fi] = *(const short8*)&wbf[fi*4096 + (it+2)*512];
    }
    #pragma unroll
    for (int mi=0;mi<4;mi++)
      #pragma unroll
      for (int fi=0;fi<4;fi++)
        acc[mi][fi] = __builtin_amdgcn_mfma_f32_16x16x32_bf16(af[mi], Bfr[it%3][fi], acc[mi][fi], 0,0,0);
  }

  float bv[4];
  #pragma unroll
  for (int fi=0;fi<4;fi++) bv[fi] = bq[wf*64 + fi*16 + i16];

  // ---- epilogue1: sigmoid -> S + block-local rowsum ----
  #pragma unroll
  for (int mi=0;mi<4;mi++) {
    float rsub[4] = {0.f,0.f,0.f,0.f};
    #pragma unroll
    for (int fi=0;fi<4;fi++) {
      #pragma unroll
      for (int r=0;r<4;r++) {
        float ph = sigmoidf_fast(acc[mi][fi][r] + bv[fi]);
        rsub[r] += ph;
        S[mi*16 + q*4 + r][wf*64 + fi*16 + i16] = f2bf(ph);
      }
    }
    #pragma unroll
    for (int r=0;r<4;r++) {
      float s = rsub[r];
      s += __shfl_xor(s,1); s += __shfl_xor(s,2); s += __shfl_xor(s,4); s += __shfl_xor(s,8);
      if (i16 == 0) atomicAdd(&rs_sh[mi*16 + q*4 + r], s);
    }
  }

  // GEMM2 B prefetch (overlaps barrier wait)
  short8 Bf2[3][4];
  #pragma unroll
  for (int ei=0;ei<4;ei++) Bf2[0][ei] = *(const short8*)&kbf[ei*4096];
  #pragma unroll
  for (int ei=0;ei<4;ei++) Bf2[1][ei] = *(const short8*)&kbf[ei*4096 + 512];

  __syncthreads();   // publish S + rs

  // ---- GEMM2: out = gate * phi @ KV ----
  #pragma unroll
  for (int i=0;i<4;i++)
    #pragma unroll
    for (int j=0;j<4;j++) acc[i][j] = (f32x4){0.f,0.f,0.f,0.f};

  #pragma unroll
  for (int it=0; it<8; it++){
    if (it < 6) {
      #pragma unroll
      for (int ei=0;ei<4;ei++)
        Bf2[(it+2)%3][ei] = *(const short8*)&kbf[ei*4096 + (it+2)*512];
    }
    short8 af[4];
    #pragma unroll
    for (int mi=0;mi<4;mi++)
      af[mi] = *(const short8*)&S[mi*16 + i16][it*32 + q*8];
    #pragma unroll
    for (int mi=0;mi<4;mi++)
      #pragma unroll
      for (int ei=0;ei<4;ei++)
        acc[mi][ei] = __builtin_amdgcn_mfma_f32_16x16x32_bf16(af[mi], Bf2[it%3][ei], acc[mi][ei],0,0,0);
  }

  #pragma unroll
  for (int mi=0;mi<4;mi++){
    #pragma unroll
    for (int r=0;r<4;r++){
      const int nl = mi*16 + q*4 + r;
      const float rs = rs_sh[nl];
      const float gate = sigmoidf_(rs) / (rs + EPS_);
      #pragma unroll
      for (int ei=0;ei<4;ei++)
        outp[((size_t)(b*4096 + n0 + nl))*256 + wf*64 + ei*16 + i16] = gate*acc[mi][ei][r];
    }
  }
}

extern "C" void kernel_launch(void* const* d_in, const int* in_sizes, int n_in,
                              void* d_out, int out_size, void* d_ws, size_t ws_size,
                              hipStream_t stream) {
  const float* Q  = (const float*)d_in[0];
  const float* K  = (const float*)d_in[1];
  const float* V  = (const float*)d_in[2];
  const float* Wq = (const float*)d_in[3];
  const float* bq = (const float*)d_in[4];
  const float* Wk = (const float*)d_in[5];
  const float* bk = (const float*)d_in[6];
  float* out = (float*)d_out;

  u16* phi_kT = (u16*)d_ws;                 // 16,777,216 bf16 TILED [b][nchunk][d][n64]
  u16* WqT    = phi_kT + 16777216;          // 65,536 (fragment order)
  u16* WkT    = WqT + 65536;                // 65,536 (fragment order)
  float* colsum = (float*)(WkT + 65536);    // 4096
  float* denom  = colsum + 4096;            // 4096
  u16* partsT = (u16*)(denom + 4096);       // 8*16*65536 bf16 (fragment-flat)
  u16* KV_nT  = partsT + 8388608;           // 1,048,576 bf16 (fragment order)

  hipMemsetAsync(colsum, 0, 8192 * sizeof(float), stream);

  prep_w<<<dim3(32), 256, 0, stream>>>(Wq, Wk, WqT, WkT);
  phi_k<<<dim3(1024), 256, 0, stream>>>(K, WkT, bk, phi_kT, colsum);
  kv_kernel<<<dim3(4, 8, 16), 256, 0, stream>>>(phi_kT, V, colsum, partsT, denom);
  kv_norm<<<dim3(64, 16), 256, 0, stream>>>(partsT, denom, KV_nT);
  out_fused<<<dim3(64, 16), 256, 0, stream>>>(Q, WqT, bq, KV_nT, out);
}